// Round 1
// baseline (89.868 us; speedup 1.0000x reference)
//
#include <hip/hip_runtime.h>
#include <hip/hip_bf16.h>
#include <stdint.h>

#define NN 4096
#define DD 1024
#define INV_T 10.0f

typedef float f32x4 __attribute__((ext_vector_type(4)));
typedef __bf16 bf16x8 __attribute__((ext_vector_type(8)));

__device__ __forceinline__ unsigned short f2bf(float x) {
  return __builtin_bit_cast(unsigned short, __float2bfloat16(x));
}

__device__ __forceinline__ void gload_lds16(const void* g, void* l) {
  __builtin_amdgcn_global_load_lds(
      (const __attribute__((address_space(1))) void*)g,
      (__attribute__((address_space(3))) void*)l, 16, 0, 0);
}

// ---------- kernel 1: row-L2-normalize -> bf16, plus exact fp32 diagonal ----------
__global__ __launch_bounds__(256) void nrm_kernel(
    const float* __restrict__ e1, const float* __restrict__ e2,
    unsigned short* __restrict__ e1n, unsigned short* __restrict__ e2n,
    float* __restrict__ log_diag, float* __restrict__ exp_diag)
{
  const int row  = blockIdx.x;
  const int tid  = threadIdx.x;
  const int lane = tid & 63;
  const int wave = tid >> 6;
  const int64_t base = (int64_t)row * DD;

  const float4 v1 = *reinterpret_cast<const float4*>(e1 + base + tid * 4);
  const float4 v2 = *reinterpret_cast<const float4*>(e2 + base + tid * 4);

  float ss1 = v1.x*v1.x + v1.y*v1.y + v1.z*v1.z + v1.w*v1.w;
  float ss2 = v2.x*v2.x + v2.y*v2.y + v2.z*v2.z + v2.w*v2.w;
  float d12 = v1.x*v2.x + v1.y*v2.y + v1.z*v2.z + v1.w*v2.w;

  #pragma unroll
  for (int off = 1; off < 64; off <<= 1) {
    ss1 += __shfl_xor(ss1, off);
    ss2 += __shfl_xor(ss2, off);
    d12 += __shfl_xor(d12, off);
  }

  __shared__ float red[3][4];
  if (lane == 0) { red[0][wave] = ss1; red[1][wave] = ss2; red[2][wave] = d12; }
  __syncthreads();
  ss1 = red[0][0] + red[0][1] + red[0][2] + red[0][3];
  ss2 = red[1][0] + red[1][1] + red[1][2] + red[1][3];
  d12 = red[2][0] + red[2][1] + red[2][2] + red[2][3];

  const float inv1 = 1.0f / fmaxf(sqrtf(ss1), 1e-12f);
  const float inv2 = 1.0f / fmaxf(sqrtf(ss2), 1e-12f);

  if (tid == 0) {
    const float ld = d12 * inv1 * inv2 * INV_T;
    log_diag[row] = ld;
    exp_diag[row] = __expf(ld);
  }

  ushort4 o1, o2;
  o1.x = f2bf(v1.x * inv1); o1.y = f2bf(v1.y * inv1);
  o1.z = f2bf(v1.z * inv1); o1.w = f2bf(v1.w * inv1);
  o2.x = f2bf(v2.x * inv2); o2.y = f2bf(v2.y * inv2);
  o2.z = f2bf(v2.z * inv2); o2.w = f2bf(v2.w * inv2);
  *reinterpret_cast<ushort4*>(e1n + base + tid * 4) = o1;
  *reinterpret_cast<ushort4*>(e2n + base + tid * 4) = o2;
}

// ---------- kernel 2: fused GEMM (e1n . e2n^T) -> exp -> row/col partial sums ----------
// m97 structure: 128x128 tile, BK=64, 4 waves (2x2), 16x16x32 bf16 MFMA,
// global_load_lds width=16 staging, linear LDS.
__global__ __launch_bounds__(256) void gemm_kernel(
    const unsigned short* __restrict__ A,   // e1n [NN][DD] bf16 bits
    const unsigned short* __restrict__ B,   // e2n [NN][DD] bf16 bits
    float* __restrict__ row_sum, float* __restrict__ col_sum)
{
  __shared__ __align__(16) unsigned short lds_a[128 * 64];
  __shared__ __align__(16) unsigned short lds_b[128 * 64];

  const int tid  = threadIdx.x;
  const int lane = tid & 63;
  const int wave = tid >> 6;
  const int wr = wave >> 1;     // wave row (0..1), 64-row sub-tile
  const int wc = wave & 1;      // wave col (0..1), 64-col sub-tile
  const int brow = blockIdx.y * 128;
  const int bcol = blockIdx.x * 128;

  // staging geometry: chunk c = wave*4+q covers tile rows [c*8, c*8+8), 1KB per chunk.
  // lane l writes bytes [l*16, l*16+16) of the chunk == row c*8+(l>>3), cols (l&7)*8..+7
  const int s_row = lane >> 3;          // 0..7 within chunk
  const int s_col = (lane & 7) * 8;     // element col within BK
  const int64_t a_off = (int64_t)(brow + wave * 32 + s_row) * DD + s_col;
  const int64_t b_off = (int64_t)(bcol + wave * 32 + s_row) * DD + s_col;
  unsigned short* const lchunk_a = lds_a + wave * 4 * 512;
  unsigned short* const lchunk_b = lds_b + wave * 4 * 512;

  // fragment geometry (16x16x32): A row = lane&15, k = (lane>>4)*8 + e
  const int fr = lane & 15;
  const int fq = lane >> 4;
  const int a_frag_base = (wr * 64 + fr) * 64 + fq * 8;
  const int b_frag_base = (wc * 64 + fr) * 64 + fq * 8;

  f32x4 acc[4][4] = {};

  for (int kt = 0; kt < DD / 64; ++kt) {
    __syncthreads();   // previous iteration's LDS reads complete before overwrite
    #pragma unroll
    for (int q = 0; q < 4; ++q) {
      gload_lds16(A + a_off + (int64_t)q * (8 * DD) + kt * 64, lchunk_a + q * 512);
      gload_lds16(B + b_off + (int64_t)q * (8 * DD) + kt * 64, lchunk_b + q * 512);
    }
    __syncthreads();   // compiler drains vmcnt(0) before this barrier -> tiles ready
    #pragma unroll
    for (int kk = 0; kk < 2; ++kk) {
      bf16x8 af[4], bfv[4];
      #pragma unroll
      for (int m = 0; m < 4; ++m)
        af[m] = *reinterpret_cast<const bf16x8*>(lds_a + a_frag_base + m * (16 * 64) + kk * 32);
      #pragma unroll
      for (int n = 0; n < 4; ++n)
        bfv[n] = *reinterpret_cast<const bf16x8*>(lds_b + b_frag_base + n * (16 * 64) + kk * 32);
      #pragma unroll
      for (int m = 0; m < 4; ++m) {
        #pragma unroll
        for (int n = 0; n < 4; ++n) {
          acc[m][n] = __builtin_amdgcn_mfma_f32_16x16x32_bf16(af[m], bfv[n], acc[m][n], 0, 0, 0);
        }
      }
    }
  }

  // ---- fused epilogue: v = exp(10*dot); accumulate row & col partial sums ----
  // C/D layout: col = lane&15 (fr), row = (lane>>4)*4 + j  (fq, reg j)
  float rowp[4][4];   // [m][j]
  float colp[4];      // [n]
  #pragma unroll
  for (int m = 0; m < 4; ++m)
    #pragma unroll
    for (int j = 0; j < 4; ++j)
      rowp[m][j] = 0.0f;
  #pragma unroll
  for (int n = 0; n < 4; ++n) colp[n] = 0.0f;

  #pragma unroll
  for (int m = 0; m < 4; ++m) {
    #pragma unroll
    for (int n = 0; n < 4; ++n) {
      #pragma unroll
      for (int j = 0; j < 4; ++j) {
        const float v = __expf(acc[m][n][j] * INV_T);
        rowp[m][j] += v;
        colp[n]    += v;
      }
    }
  }

  // row sums: reduce across the 16 col-lanes (xor 1,2,4,8), then 1 atomic per row
  #pragma unroll
  for (int m = 0; m < 4; ++m) {
    #pragma unroll
    for (int j = 0; j < 4; ++j) {
      float r = rowp[m][j];
      r += __shfl_xor(r, 1);
      r += __shfl_xor(r, 2);
      r += __shfl_xor(r, 4);
      r += __shfl_xor(r, 8);
      if (fr == 0) {
        atomicAdd(&row_sum[brow + wr * 64 + m * 16 + fq * 4 + j], r);
      }
    }
  }
  // col sums: reduce across the 4 row-groups (xor 16,32), then 1 atomic per col
  #pragma unroll
  for (int n = 0; n < 4; ++n) {
    float c = colp[n];
    c += __shfl_xor(c, 16);
    c += __shfl_xor(c, 32);
    if (lane < 16) {
      atomicAdd(&col_sum[bcol + wc * 64 + n * 16 + fr], c);
    }
  }
}

// ---------- kernel 3: final scalar reduction ----------
__global__ __launch_bounds__(256) void fin_kernel(
    const float* __restrict__ row_sum, const float* __restrict__ col_sum,
    const float* __restrict__ log_diag, const float* __restrict__ exp_diag,
    float* __restrict__ out)
{
  const int tid  = threadIdx.x;
  const int lane = tid & 63;
  const int wave = tid >> 6;
  float a0 = 0.0f, a1 = 0.0f;
  for (int i = tid; i < NN; i += 256) {
    const float ld = log_diag[i];
    const float ed = exp_diag[i];
    a0 += logf(row_sum[i] - ed) - ld;   // -sim_12 contribution
    a1 += logf(col_sum[i] - ed) - ld;   // -sim_21 contribution
  }
  #pragma unroll
  for (int off = 1; off < 64; off <<= 1) {
    a0 += __shfl_xor(a0, off);
    a1 += __shfl_xor(a1, off);
  }
  __shared__ float r0[4], r1[4];
  if (lane == 0) { r0[wave] = a0; r1[wave] = a1; }
  __syncthreads();
  if (tid == 0) {
    out[0] = r0[0] + r0[1] + r0[2] + r0[3];
    out[1] = r1[0] + r1[1] + r1[2] + r1[3];
  }
}

extern "C" void kernel_launch(void* const* d_in, const int* in_sizes, int n_in,
                              void* d_out, int out_size, void* d_ws, size_t ws_size,
                              hipStream_t stream) {
  const float* e1 = (const float*)d_in[0];
  const float* e2 = (const float*)d_in[1];
  float* out = (float*)d_out;

  char* ws = (char*)d_ws;
  unsigned short* e1n = (unsigned short*)ws;                            // 8 MB
  unsigned short* e2n = (unsigned short*)(ws + (size_t)NN * DD * 2);    // 8 MB
  float* log_diag = (float*)(ws + (size_t)NN * DD * 4);                 // 16 KB
  float* exp_diag = log_diag + NN;                                      // 16 KB
  float* row_sum  = exp_diag + NN;                                      // 16 KB
  float* col_sum  = row_sum + NN;                                       // 16 KB

  hipMemsetAsync(row_sum, 0, 2 * NN * sizeof(float), stream);  // row_sum + col_sum contiguous
  nrm_kernel<<<NN, 256, 0, stream>>>(e1, e2, e1n, e2n, log_diag, exp_diag);
  gemm_kernel<<<dim3(NN / 128, NN / 128), 256, 0, stream>>>(e1n, e2n, row_sum, col_sum);
  fin_kernel<<<1, 256, 0, stream>>>(row_sum, col_sum, log_diag, exp_diag, out);
}

// Round 2
// 81.145 us; speedup vs baseline: 1.1075x; 1.1075x over previous
//
#include <hip/hip_runtime.h>
#include <hip/hip_bf16.h>
#include <stdint.h>

#define NN 4096
#define DD 1024
#define INV_T 10.0f

typedef float f32x4 __attribute__((ext_vector_type(4)));
typedef __bf16 bf16x8 __attribute__((ext_vector_type(8)));

__device__ __forceinline__ unsigned short f2bf(float x) {
  return __builtin_bit_cast(unsigned short, __float2bfloat16(x));
}

__device__ __forceinline__ void gload_lds16(const void* g, void* l) {
  __builtin_amdgcn_global_load_lds(
      (const __attribute__((address_space(1))) void*)g,
      (__attribute__((address_space(3))) void*)l, 16, 0, 0);
}

// ---------- kernel 1: row-L2-normalize -> bf16, plus exact fp32 diagonal ----------
__global__ __launch_bounds__(256) void nrm_kernel(
    const float* __restrict__ e1, const float* __restrict__ e2,
    unsigned short* __restrict__ e1n, unsigned short* __restrict__ e2n,
    float* __restrict__ log_diag, float* __restrict__ exp_diag)
{
  const int row  = blockIdx.x;
  const int tid  = threadIdx.x;
  const int lane = tid & 63;
  const int wave = tid >> 6;
  const int64_t base = (int64_t)row * DD;

  const float4 v1 = *reinterpret_cast<const float4*>(e1 + base + tid * 4);
  const float4 v2 = *reinterpret_cast<const float4*>(e2 + base + tid * 4);

  float ss1 = v1.x*v1.x + v1.y*v1.y + v1.z*v1.z + v1.w*v1.w;
  float ss2 = v2.x*v2.x + v2.y*v2.y + v2.z*v2.z + v2.w*v2.w;
  float d12 = v1.x*v2.x + v1.y*v2.y + v1.z*v2.z + v1.w*v2.w;

  #pragma unroll
  for (int off = 1; off < 64; off <<= 1) {
    ss1 += __shfl_xor(ss1, off);
    ss2 += __shfl_xor(ss2, off);
    d12 += __shfl_xor(d12, off);
  }

  __shared__ float red[3][4];
  if (lane == 0) { red[0][wave] = ss1; red[1][wave] = ss2; red[2][wave] = d12; }
  __syncthreads();
  ss1 = red[0][0] + red[0][1] + red[0][2] + red[0][3];
  ss2 = red[1][0] + red[1][1] + red[1][2] + red[1][3];
  d12 = red[2][0] + red[2][1] + red[2][2] + red[2][3];

  const float inv1 = 1.0f / fmaxf(sqrtf(ss1), 1e-12f);
  const float inv2 = 1.0f / fmaxf(sqrtf(ss2), 1e-12f);

  if (tid == 0) {
    const float ld = d12 * inv1 * inv2 * INV_T;
    log_diag[row] = ld;
    exp_diag[row] = __expf(ld);
  }

  ushort4 o1, o2;
  o1.x = f2bf(v1.x * inv1); o1.y = f2bf(v1.y * inv1);
  o1.z = f2bf(v1.z * inv1); o1.w = f2bf(v1.w * inv1);
  o2.x = f2bf(v2.x * inv2); o2.y = f2bf(v2.y * inv2);
  o2.z = f2bf(v2.z * inv2); o2.w = f2bf(v2.w * inv2);
  *reinterpret_cast<ushort4*>(e1n + base + tid * 4) = o1;
  *reinterpret_cast<ushort4*>(e2n + base + tid * 4) = o2;
}

// ---------- kernel 2: fused 256x256-tile phased GEMM -> exp -> row/col sums ----------
// 8 waves (2M x 4N), BK=64, double-buffered LDS (128 KiB), raw s_barrier phases,
// one vmcnt(0) per K-tile boundary, T2 swizzle (pre-swizzled global src + swizzled
// ds_read), setprio around MFMA clusters.
__global__ __launch_bounds__(512, 2) void gemm_kernel(
    const unsigned short* __restrict__ A,   // e1n [NN][DD] bf16 bits
    const unsigned short* __restrict__ B,   // e2n [NN][DD] bf16 bits
    float* __restrict__ row_sum, float* __restrict__ col_sum)
{
  __shared__ __align__(16) unsigned short lds_a[2][16384];  // [slot][256r x 64c]
  __shared__ __align__(16) unsigned short lds_b[2][16384];

  const int tid  = threadIdx.x;
  const int lane = tid & 63;
  const int wave = tid >> 6;          // 0..7
  const int wm = wave >> 2;           // 0..1 : rows [wm*128, +128)
  const int wn = wave & 3;            // 0..3 : cols [wn*64, +64)
  const int brow = blockIdx.y * 256;
  const int bcol = blockIdx.x * 256;

  // ---- staging geometry (pre-swizzled global source, linear LDS dest) ----
  // round q covers tile rows [q*64, +64); within a round, wave covers 8 rows.
  // lane l: row = q*64 + wave*8 + (l>>3); dest 16B-slot = l&7;
  // source slot = (l&7) ^ (row&7) = (l&7) ^ (l>>3)  ->  LDS[row][s] = G[row][s^(row&7)]
  const int s_sub  = lane >> 3;                    // row within wave's 8
  const int s_swz  = ((lane & 7) ^ s_sub) * 8;     // swizzled source col (elems)
  const int a_rowb = brow + wave * 8 + s_sub;
  const int b_rowb = bcol + wave * 8 + s_sub;
  const int lds_st = wave * 512;                   // + q*4096 (elems)

  // ---- fragment geometry (16x16x32): A row = lane&15, k = (lane>>4)*8 + kk*32 ----
  const int fr = lane & 15;
  const int fq = lane >> 4;
  const int a_base0 = (wm * 128 + fr) * 64;        // elem index of row, col 0
  const int b_base0 = (wn * 64 + fr) * 64;
  const int sw0 = ((fq    ) ^ (fr & 7)) * 8;       // swizzled 16B slot, kk=0
  const int sw1 = ((fq + 4) ^ (fr & 7)) * 8;       // kk=1

  f32x4 acc[8][4] = {};

  // ---- prologue: stage K-tile 0 into slot 0 ----
  #pragma unroll
  for (int q = 0; q < 4; ++q) {
    gload_lds16(A + (a_rowb + q * 64) * DD + s_swz, &lds_a[0][q * 4096 + lds_st]);
    gload_lds16(B + (b_rowb + q * 64) * DD + s_swz, &lds_b[0][q * 4096 + lds_st]);
  }

  for (int kt = 0; kt < DD / 64; ++kt) {
    const int cur = kt & 1;
    const int nxt = cur ^ 1;
    // staged data for this K-tile (issued >=1 phase ago) must be in LDS
    asm volatile("s_waitcnt vmcnt(0)" ::: "memory");
    __builtin_amdgcn_s_barrier();

    #pragma unroll
    for (int p = 0; p < 4; ++p) {
      const int mh = p >> 1;
      const int nh = p & 1;

      // stage one round of K-tile kt+1 (A + B) into the other slot
      if (kt < DD / 64 - 1) {
        const int kc = (kt + 1) * 64;
        gload_lds16(A + (a_rowb + p * 64) * DD + kc + s_swz, &lds_a[nxt][p * 4096 + lds_st]);
        gload_lds16(B + (b_rowb + p * 64) * DD + kc + s_swz, &lds_b[nxt][p * 4096 + lds_st]);
      }

      // 12 ds_read_b128 for this phase's quadrant
      bf16x8 af[4][2], bfv[2][2];
      #pragma unroll
      for (int mi = 0; mi < 4; ++mi) {
        const int rb = a_base0 + (mh * 4 + mi) * 1024;   // +16 rows per mi
        af[mi][0] = *reinterpret_cast<const bf16x8*>(&lds_a[cur][rb + sw0]);
        af[mi][1] = *reinterpret_cast<const bf16x8*>(&lds_a[cur][rb + sw1]);
      }
      #pragma unroll
      for (int ni = 0; ni < 2; ++ni) {
        const int rb = b_base0 + (nh * 2 + ni) * 1024;
        bfv[ni][0] = *reinterpret_cast<const bf16x8*>(&lds_b[cur][rb + sw0]);
        bfv[ni][1] = *reinterpret_cast<const bf16x8*>(&lds_b[cur][rb + sw1]);
      }

      __builtin_amdgcn_s_barrier();
      asm volatile("s_waitcnt lgkmcnt(0)" ::: "memory");
      __builtin_amdgcn_sched_barrier(0);
      __builtin_amdgcn_s_setprio(1);
      #pragma unroll
      for (int kk = 0; kk < 2; ++kk) {
        #pragma unroll
        for (int mi = 0; mi < 4; ++mi) {
          #pragma unroll
          for (int ni = 0; ni < 2; ++ni) {
            acc[mh * 4 + mi][nh * 2 + ni] = __builtin_amdgcn_mfma_f32_16x16x32_bf16(
                af[mi][kk], bfv[ni][kk], acc[mh * 4 + mi][nh * 2 + ni], 0, 0, 0);
          }
        }
      }
      __builtin_amdgcn_s_setprio(0);
      __builtin_amdgcn_s_barrier();
    }
  }

  // ---- fused epilogue: v = exp(10*dot); row & col partial sums ----
  // C/D layout: col = fr, row = fq*4 + j  (within each 16x16 fragment)
  float rowp[8][4];
  float colp[4];
  #pragma unroll
  for (int mi = 0; mi < 8; ++mi)
    #pragma unroll
    for (int j = 0; j < 4; ++j) rowp[mi][j] = 0.0f;
  #pragma unroll
  for (int ni = 0; ni < 4; ++ni) colp[ni] = 0.0f;

  #pragma unroll
  for (int mi = 0; mi < 8; ++mi) {
    #pragma unroll
    for (int ni = 0; ni < 4; ++ni) {
      #pragma unroll
      for (int j = 0; j < 4; ++j) {
        const float v = __expf(acc[mi][ni][j] * INV_T);
        rowp[mi][j] += v;
        colp[ni]    += v;
      }
    }
  }

  // row sums: reduce across 16 col-lanes (fr bits), 1 atomic per row per wave
  #pragma unroll
  for (int mi = 0; mi < 8; ++mi) {
    #pragma unroll
    for (int j = 0; j < 4; ++j) {
      float r = rowp[mi][j];
      r += __shfl_xor(r, 1);
      r += __shfl_xor(r, 2);
      r += __shfl_xor(r, 4);
      r += __shfl_xor(r, 8);
      if (fr == 0) {
        atomicAdd(&row_sum[brow + wm * 128 + mi * 16 + fq * 4 + j], r);
      }
    }
  }
  // col sums: reduce across the 4 fq row-groups, 1 atomic per col per wave
  #pragma unroll
  for (int ni = 0; ni < 4; ++ni) {
    float c = colp[ni];
    c += __shfl_xor(c, 16);
    c += __shfl_xor(c, 32);
    if (lane < 16) {
      atomicAdd(&col_sum[bcol + wn * 64 + ni * 16 + fr], c);
    }
  }
}

// ---------- kernel 3: final scalar reduction ----------
__global__ __launch_bounds__(1024) void fin_kernel(
    const float* __restrict__ row_sum, const float* __restrict__ col_sum,
    const float* __restrict__ log_diag, const float* __restrict__ exp_diag,
    float* __restrict__ out)
{
  const int tid  = threadIdx.x;
  const int lane = tid & 63;
  const int wave = tid >> 6;
  float a0 = 0.0f, a1 = 0.0f;
  #pragma unroll
  for (int k = 0; k < NN / 1024; ++k) {
    const int i = tid + k * 1024;
    const float ld = log_diag[i];
    const float ed = exp_diag[i];
    a0 += logf(row_sum[i] - ed) - ld;   // -sim_12 contribution
    a1 += logf(col_sum[i] - ed) - ld;   // -sim_21 contribution
  }
  #pragma unroll
  for (int off = 1; off < 64; off <<= 1) {
    a0 += __shfl_xor(a0, off);
    a1 += __shfl_xor(a1, off);
  }
  __shared__ float r0[16], r1[16];
  if (lane == 0) { r0[wave] = a0; r1[wave] = a1; }
  __syncthreads();
  if (tid == 0) {
    float s0 = 0.0f, s1 = 0.0f;
    #pragma unroll
    for (int w = 0; w < 16; ++w) { s0 += r0[w]; s1 += r1[w]; }
    out[0] = s0;
    out[1] = s1;
  }
}

extern "C" void kernel_launch(void* const* d_in, const int* in_sizes, int n_in,
                              void* d_out, int out_size, void* d_ws, size_t ws_size,
                              hipStream_t stream) {
  const float* e1 = (const float*)d_in[0];
  const float* e2 = (const float*)d_in[1];
  float* out = (float*)d_out;

  char* ws = (char*)d_ws;
  unsigned short* e1n = (unsigned short*)ws;                            // 8 MB
  unsigned short* e2n = (unsigned short*)(ws + (size_t)NN * DD * 2);    // 8 MB
  float* log_diag = (float*)(ws + (size_t)NN * DD * 4);                 // 16 KB
  float* exp_diag = log_diag + NN;                                      // 16 KB
  float* row_sum  = exp_diag + NN;                                      // 16 KB
  float* col_sum  = row_sum + NN;                                       // 16 KB

  hipMemsetAsync(row_sum, 0, 2 * NN * sizeof(float), stream);  // row_sum + col_sum contiguous
  nrm_kernel<<<NN, 256, 0, stream>>>(e1, e2, e1n, e2n, log_diag, exp_diag);
  gemm_kernel<<<dim3(NN / 256, NN / 256), 512, 0, stream>>>(e1n, e2n, row_sum, col_sum);
  fin_kernel<<<1, 1024, 0, stream>>>(row_sum, col_sum, log_diag, exp_diag, out);
}

// Round 3
// 62.642 us; speedup vs baseline: 1.4346x; 1.2954x over previous
//
#include <hip/hip_runtime.h>
#include <hip/hip_bf16.h>
#include <stdint.h>

#define NN 4096
#define DD 1024
#define INV_T 10.0f

typedef float f32x4 __attribute__((ext_vector_type(4)));
typedef __bf16 bf16x8 __attribute__((ext_vector_type(8)));

__device__ __forceinline__ unsigned short f2bf(float x) {
  return __builtin_bit_cast(unsigned short, __float2bfloat16(x));
}

__device__ __forceinline__ void gload_lds16(const void* g, void* l) {
  __builtin_amdgcn_global_load_lds(
      (const __attribute__((address_space(1))) void*)g,
      (__attribute__((address_space(3))) void*)l, 16, 0, 0);
}

// ---------- kernel 1: row-L2-normalize -> bf16, plus exact fp32 diagonal ----------
__global__ __launch_bounds__(256) void nrm_kernel(
    const float* __restrict__ e1, const float* __restrict__ e2,
    unsigned short* __restrict__ e1n, unsigned short* __restrict__ e2n,
    float* __restrict__ log_diag, float* __restrict__ exp_diag)
{
  const int row  = blockIdx.x;
  const int tid  = threadIdx.x;
  const int lane = tid & 63;
  const int wave = tid >> 6;
  const int64_t base = (int64_t)row * DD;

  const float4 v1 = *reinterpret_cast<const float4*>(e1 + base + tid * 4);
  const float4 v2 = *reinterpret_cast<const float4*>(e2 + base + tid * 4);

  float ss1 = v1.x*v1.x + v1.y*v1.y + v1.z*v1.z + v1.w*v1.w;
  float ss2 = v2.x*v2.x + v2.y*v2.y + v2.z*v2.z + v2.w*v2.w;
  float d12 = v1.x*v2.x + v1.y*v2.y + v1.z*v2.z + v1.w*v2.w;

  #pragma unroll
  for (int off = 1; off < 64; off <<= 1) {
    ss1 += __shfl_xor(ss1, off);
    ss2 += __shfl_xor(ss2, off);
    d12 += __shfl_xor(d12, off);
  }

  __shared__ float red[3][4];
  if (lane == 0) { red[0][wave] = ss1; red[1][wave] = ss2; red[2][wave] = d12; }
  __syncthreads();
  ss1 = red[0][0] + red[0][1] + red[0][2] + red[0][3];
  ss2 = red[1][0] + red[1][1] + red[1][2] + red[1][3];
  d12 = red[2][0] + red[2][1] + red[2][2] + red[2][3];

  const float inv1 = 1.0f / fmaxf(sqrtf(ss1), 1e-12f);
  const float inv2 = 1.0f / fmaxf(sqrtf(ss2), 1e-12f);

  if (tid == 0) {
    const float ld = d12 * inv1 * inv2 * INV_T;
    log_diag[row] = ld;
    exp_diag[row] = __expf(ld);
  }

  ushort4 o1, o2;
  o1.x = f2bf(v1.x * inv1); o1.y = f2bf(v1.y * inv1);
  o1.z = f2bf(v1.z * inv1); o1.w = f2bf(v1.w * inv1);
  o2.x = f2bf(v2.x * inv2); o2.y = f2bf(v2.y * inv2);
  o2.z = f2bf(v2.z * inv2); o2.w = f2bf(v2.w * inv2);
  *reinterpret_cast<ushort4*>(e1n + base + tid * 4) = o1;
  *reinterpret_cast<ushort4*>(e2n + base + tid * 4) = o2;
}

// stage one k-half (256 rows x 32 cols) of one matrix into LDS, linearly.
// dst layout: [256][32] ushort. 2 gloads per lane; wave-uniform LDS base.
__device__ __forceinline__ void stage_khalf(
    const unsigned short* __restrict__ src, int row_base, int kcol,
    unsigned short (*dst)[32], int wave, int lane)
{
  const int r0 = wave * 16 + (lane >> 2);
  const int c  = (lane & 3) * 8;
  gload_lds16(src + (int64_t)(row_base + r0) * DD + kcol + c,
              &dst[wave * 16][0]);
  gload_lds16(src + (int64_t)(row_base + 128 + r0) * DD + kcol + c,
              &dst[128 + wave * 16][0]);
}

// ---------- kernel 2: fused 256x256 GEMM, derived-wait 4-phase schedule ----------
// 8 waves (2M x 4N), BK=64 split as 2 k-halves. LDS [slot][kk][256][32]
// (64B rows -> ds_read_b128 at the bank floor, no swizzle needed).
// Per phase: 4-8 ds_read_b128 + 1 stage-step (2 gload_lds) + 16 MFMA.
// vmcnt(4) at p1/p3 guards data issued 3-4 phases earlier; 2 barriers/tile.
__global__ __launch_bounds__(512, 2) void gemm_kernel(
    const unsigned short* __restrict__ A,   // e1n [NN][DD] bf16 bits
    const unsigned short* __restrict__ B,   // e2n [NN][DD] bf16 bits
    float* __restrict__ row_sum, float* __restrict__ col_sum)
{
  __shared__ __align__(16) unsigned short lds_a[2][2][256][32];  // 64 KiB
  __shared__ __align__(16) unsigned short lds_b[2][2][256][32];  // 64 KiB

  const int tid  = threadIdx.x;
  const int lane = tid & 63;
  const int wave = tid >> 6;          // 0..7
  const int wm = wave >> 2;           // 0..1 : rows [wm*128, +128)
  const int wn = wave & 3;            // 0..3 : cols [wn*64, +64)

  // XCD-aware block swizzle: each XCD owns a 4x8 rectangle of the 16x16 grid
  const int bid = blockIdx.x;
  const int xcd = bid & 7;
  const int k   = bid >> 3;           // 0..31 within XCD
  const int brow = ((xcd >> 1) * 4 + (k >> 3)) * 256;
  const int bcol = ((xcd & 1) * 8 + (k & 7)) * 256;

  const int fr = lane & 15;
  const int fq = lane >> 4;

  f32x4 acc[8][4] = {};

  // prologue: stage tile 0 (order: A-k0, B-k0, A-k1, B-k1)
  stage_khalf(A, brow, 0,  lds_a[0][0], wave, lane);
  stage_khalf(B, bcol, 0,  lds_b[0][0], wave, lane);
  stage_khalf(A, brow, 32, lds_a[0][1], wave, lane);
  stage_khalf(B, bcol, 32, lds_b[0][1], wave, lane);

#define MFMA_CLUSTER(MH)                                                      \
  asm volatile("s_waitcnt lgkmcnt(0)" ::: "memory");                          \
  __builtin_amdgcn_sched_barrier(0);                                          \
  __builtin_amdgcn_s_setprio(1);                                              \
  _Pragma("unroll")                                                           \
  for (int i = 0; i < 4; ++i) {                                               \
    _Pragma("unroll")                                                         \
    for (int j = 0; j < 4; ++j) {                                             \
      acc[(MH)*4 + i][j] = __builtin_amdgcn_mfma_f32_16x16x32_bf16(           \
          af[i], bfv[j], acc[(MH)*4 + i][j], 0, 0, 0);                        \
    }                                                                         \
  }                                                                           \
  __builtin_amdgcn_s_setprio(0);

  #pragma unroll 2
  for (int t = 0; t < DD / 64; ++t) {
    const int c = t & 1;
    const int n = c ^ 1;
    const int kn = (t + 1) * 64;
    const bool pf = (t < DD / 64 - 1);
    bf16x8 af[4], bfv[4];

    // ---- phase 1: kk=0, mh=0 ----
    asm volatile("s_waitcnt vmcnt(4)" ::: "memory");  // A-k0,B-k0 of tile t landed
    __builtin_amdgcn_s_barrier();
    #pragma unroll
    for (int i = 0; i < 4; ++i)
      af[i] = *reinterpret_cast<const bf16x8*>(&lds_a[c][0][wm*128 + i*16 + fr][fq*8]);
    #pragma unroll
    for (int i = 0; i < 4; ++i)
      bfv[i] = *reinterpret_cast<const bf16x8*>(&lds_b[c][0][wn*64 + i*16 + fr][fq*8]);
    if (pf) stage_khalf(A, brow, kn, lds_a[n][0], wave, lane);
    MFMA_CLUSTER(0)

    // ---- phase 2: kk=0, mh=1 (reuse bfv) ----
    #pragma unroll
    for (int i = 0; i < 4; ++i)
      af[i] = *reinterpret_cast<const bf16x8*>(&lds_a[c][0][wm*128 + 64 + i*16 + fr][fq*8]);
    if (pf) stage_khalf(B, bcol, kn, lds_b[n][0], wave, lane);
    MFMA_CLUSTER(1)

    // ---- phase 3: kk=1, mh=0 ----
    if (pf) { asm volatile("s_waitcnt vmcnt(4)" ::: "memory"); }
    else    { asm volatile("s_waitcnt vmcnt(0)" ::: "memory"); }
    __builtin_amdgcn_s_barrier();
    #pragma unroll
    for (int i = 0; i < 4; ++i)
      af[i] = *reinterpret_cast<const bf16x8*>(&lds_a[c][1][wm*128 + i*16 + fr][fq*8]);
    #pragma unroll
    for (int i = 0; i < 4; ++i)
      bfv[i] = *reinterpret_cast<const bf16x8*>(&lds_b[c][1][wn*64 + i*16 + fr][fq*8]);
    if (pf) stage_khalf(A, brow, kn + 32, lds_a[n][1], wave, lane);
    MFMA_CLUSTER(0)

    // ---- phase 4: kk=1, mh=1 (reuse bfv) ----
    #pragma unroll
    for (int i = 0; i < 4; ++i)
      af[i] = *reinterpret_cast<const bf16x8*>(&lds_a[c][1][wm*128 + 64 + i*16 + fr][fq*8]);
    if (pf) stage_khalf(B, bcol, kn + 32, lds_b[n][1], wave, lane);
    MFMA_CLUSTER(1)
  }
#undef MFMA_CLUSTER

  // ---- fused epilogue: v = exp(10*dot); row & col partial sums ----
  // C/D layout: col = fr, row = fq*4 + j (within each 16x16 fragment)
  float rowp[8][4];
  float colp[4];
  #pragma unroll
  for (int mi = 0; mi < 8; ++mi)
    #pragma unroll
    for (int j = 0; j < 4; ++j) rowp[mi][j] = 0.0f;
  #pragma unroll
  for (int ni = 0; ni < 4; ++ni) colp[ni] = 0.0f;

  #pragma unroll
  for (int mi = 0; mi < 8; ++mi) {
    #pragma unroll
    for (int ni = 0; ni < 4; ++ni) {
      #pragma unroll
      for (int j = 0; j < 4; ++j) {
        const float v = __expf(acc[mi][ni][j] * INV_T);
        rowp[mi][j] += v;
        colp[ni]    += v;
      }
    }
  }

  // row sums: reduce across 16 col-lanes, 1 atomic per row per wave
  #pragma unroll
  for (int mi = 0; mi < 8; ++mi) {
    #pragma unroll
    for (int j = 0; j < 4; ++j) {
      float r = rowp[mi][j];
      r += __shfl_xor(r, 1);
      r += __shfl_xor(r, 2);
      r += __shfl_xor(r, 4);
      r += __shfl_xor(r, 8);
      if (fr == 0) {
        atomicAdd(&row_sum[brow + wm * 128 + mi * 16 + fq * 4 + j], r);
      }
    }
  }
  // col sums: reduce across the 4 fq row-groups, 1 atomic per col per wave
  #pragma unroll
  for (int ni = 0; ni < 4; ++ni) {
    float cc = colp[ni];
    cc += __shfl_xor(cc, 16);
    cc += __shfl_xor(cc, 32);
    if (lane < 16) {
      atomicAdd(&col_sum[bcol + wn * 64 + ni * 16 + fr], cc);
    }
  }
}

// ---------- kernel 3: final scalar reduction (block 0 -> rows, block 1 -> cols) ----------
__global__ __launch_bounds__(1024) void fin_kernel(
    const float* __restrict__ row_sum, const float* __restrict__ col_sum,
    const float* __restrict__ log_diag, const float* __restrict__ exp_diag,
    float* __restrict__ out)
{
  const int tid  = threadIdx.x;
  const int lane = tid & 63;
  const int wave = tid >> 6;
  const float* sums = (blockIdx.x == 0) ? row_sum : col_sum;
  float a = 0.0f;
  #pragma unroll
  for (int kk = 0; kk < NN / 1024; ++kk) {
    const int i = tid + kk * 1024;
    a += logf(sums[i] - exp_diag[i]) - log_diag[i];
  }
  #pragma unroll
  for (int off = 1; off < 64; off <<= 1) a += __shfl_xor(a, off);
  __shared__ float r0[16];
  if (lane == 0) r0[wave] = a;
  __syncthreads();
  if (tid == 0) {
    float s = 0.0f;
    #pragma unroll
    for (int w = 0; w < 16; ++w) s += r0[w];
    out[blockIdx.x] = s;
  }
}

extern "C" void kernel_launch(void* const* d_in, const int* in_sizes, int n_in,
                              void* d_out, int out_size, void* d_ws, size_t ws_size,
                              hipStream_t stream) {
  const float* e1 = (const float*)d_in[0];
  const float* e2 = (const float*)d_in[1];
  float* out = (float*)d_out;

  char* ws = (char*)d_ws;
  unsigned short* e1n = (unsigned short*)ws;                            // 8 MB
  unsigned short* e2n = (unsigned short*)(ws + (size_t)NN * DD * 2);    // 8 MB
  float* log_diag = (float*)(ws + (size_t)NN * DD * 4);                 // 16 KB
  float* exp_diag = log_diag + NN;                                      // 16 KB
  float* row_sum  = exp_diag + NN;                                      // 16 KB
  float* col_sum  = row_sum + NN;                                       // 16 KB

  hipMemsetAsync(row_sum, 0, 2 * NN * sizeof(float), stream);  // row_sum + col_sum contiguous
  nrm_kernel<<<NN, 256, 0, stream>>>(e1, e2, e1n, e2n, log_diag, exp_diag);
  gemm_kernel<<<256, 512, 0, stream>>>(e1n, e2n, row_sum, col_sum);
  fin_kernel<<<2, 1024, 0, stream>>>(row_sum, col_sum, log_diag, exp_diag, out);
}

// Round 4
// 57.871 us; speedup vs baseline: 1.5529x; 1.0824x over previous
//
#include <hip/hip_runtime.h>
#include <hip/hip_bf16.h>
#include <stdint.h>

#define NN 4096
#define DD 1024
#define INV_T 10.0f

typedef float f32x4 __attribute__((ext_vector_type(4)));
typedef __bf16 bf16x8 __attribute__((ext_vector_type(8)));

__device__ __forceinline__ unsigned short f2bf(float x) {
  return __builtin_bit_cast(unsigned short, __float2bfloat16(x));
}

__device__ __forceinline__ void gload_lds16(const void* g, void* l) {
  __builtin_amdgcn_global_load_lds(
      (const __attribute__((address_space(1))) void*)g,
      (__attribute__((address_space(3))) void*)l, 16, 0, 0);
}

// ---------- kernel 1: row-L2-normalize -> bf16, exact fp32 diagonal, zero sums ----------
__global__ __launch_bounds__(256) void nrm_kernel(
    const float* __restrict__ e1, const float* __restrict__ e2,
    unsigned short* __restrict__ e1n, unsigned short* __restrict__ e2n,
    float* __restrict__ log_diag, float* __restrict__ exp_diag,
    float* __restrict__ row_sum, float* __restrict__ col_sum)
{
  const int row  = blockIdx.x;
  const int tid  = threadIdx.x;
  const int lane = tid & 63;
  const int wave = tid >> 6;
  const int64_t base = (int64_t)row * DD;

  const float4 v1 = *reinterpret_cast<const float4*>(e1 + base + tid * 4);
  const float4 v2 = *reinterpret_cast<const float4*>(e2 + base + tid * 4);

  float ss1 = v1.x*v1.x + v1.y*v1.y + v1.z*v1.z + v1.w*v1.w;
  float ss2 = v2.x*v2.x + v2.y*v2.y + v2.z*v2.z + v2.w*v2.w;
  float d12 = v1.x*v2.x + v1.y*v2.y + v1.z*v2.z + v1.w*v2.w;

  #pragma unroll
  for (int off = 1; off < 64; off <<= 1) {
    ss1 += __shfl_xor(ss1, off);
    ss2 += __shfl_xor(ss2, off);
    d12 += __shfl_xor(d12, off);
  }

  __shared__ float red[3][4];
  if (lane == 0) { red[0][wave] = ss1; red[1][wave] = ss2; red[2][wave] = d12; }
  __syncthreads();
  ss1 = red[0][0] + red[0][1] + red[0][2] + red[0][3];
  ss2 = red[1][0] + red[1][1] + red[1][2] + red[1][3];
  d12 = red[2][0] + red[2][1] + red[2][2] + red[2][3];

  const float inv1 = 1.0f / fmaxf(sqrtf(ss1), 1e-12f);
  const float inv2 = 1.0f / fmaxf(sqrtf(ss2), 1e-12f);

  if (tid == 0) {
    const float ld = d12 * inv1 * inv2 * INV_T;
    log_diag[row] = ld;
    exp_diag[row] = __expf(ld);
    row_sum[row] = 0.0f;          // replaces the memset dispatch
    col_sum[row] = 0.0f;
  }

  ushort4 o1, o2;
  o1.x = f2bf(v1.x * inv1); o1.y = f2bf(v1.y * inv1);
  o1.z = f2bf(v1.z * inv1); o1.w = f2bf(v1.w * inv1);
  o2.x = f2bf(v2.x * inv2); o2.y = f2bf(v2.y * inv2);
  o2.z = f2bf(v2.z * inv2); o2.w = f2bf(v2.w * inv2);
  *reinterpret_cast<ushort4*>(e1n + base + tid * 4) = o1;
  *reinterpret_cast<ushort4*>(e2n + base + tid * 4) = o2;
}

// stage one k-half (256 rows x 32 cols) into LDS, linear dest, XOR-swizzled source.
// phys[row][s] = G[row][ s ^ ((row>>1)&3) ]  (16B slots). lane l: row = r0+(l>>2),
// slot = l&3  ->  source slot = (l&3) ^ ((l>>3)&3).
__device__ __forceinline__ void stage_khalf(
    const unsigned short* __restrict__ src, int row_base, int kcol,
    unsigned short (*dst)[32], int wave, int lane)
{
  const int r0 = wave * 16 + (lane >> 2);
  const int c  = ((lane & 3) ^ ((lane >> 3) & 3)) * 8;
  gload_lds16(src + (int64_t)(row_base + r0) * DD + kcol + c,
              &dst[wave * 16][0]);
  gload_lds16(src + (int64_t)(row_base + 128 + r0) * DD + kcol + c,
              &dst[128 + wave * 16][0]);
}

// ---------- kernel 2: fused 256x256 GEMM, 2-phase/tile derived-wait schedule ----------
// 8 waves (2M x 4N), BK=64 as 2 k-halves. LDS [slot][kk][256][32], XOR bank swizzle
// (16-lane quarter spreads over all 8 bank groups -> conflict floor).
// Per phase: 12 ds_read_b128 + 4 stage gloads + 32 MFMA; 1 barrier; vmcnt(4).
__global__ __launch_bounds__(512, 2) void gemm_kernel(
    const unsigned short* __restrict__ A,   // e1n [NN][DD] bf16 bits
    const unsigned short* __restrict__ B,   // e2n [NN][DD] bf16 bits
    float* __restrict__ row_sum, float* __restrict__ col_sum)
{
  __shared__ __align__(16) unsigned short lds_a[2][2][256][32];  // 64 KiB
  __shared__ __align__(16) unsigned short lds_b[2][2][256][32];  // 64 KiB

  const int tid  = threadIdx.x;
  const int lane = tid & 63;
  const int wave = tid >> 6;          // 0..7
  const int wm = wave >> 2;           // 0..1 : rows [wm*128, +128)
  const int wn = wave & 3;            // 0..3 : cols [wn*64, +64)

  // XCD-aware block swizzle: each XCD owns a 4x8 rectangle of the 16x16 grid
  const int bid = blockIdx.x;
  const int xcd = bid & 7;
  const int k   = bid >> 3;           // 0..31 within XCD
  const int brow = ((xcd >> 1) * 4 + (k >> 3)) * 256;
  const int bcol = ((xcd & 1) * 8 + (k & 7)) * 256;

  const int fr = lane & 15;
  const int fq = lane >> 4;
  const int rslot = (fq ^ ((fr >> 1) & 3)) * 8;   // swizzled read col (elems)

  f32x4 acc[8][4] = {};

  // prologue: stage tile 0 (order: A-k0, B-k0, A-k1, B-k1)
  stage_khalf(A, brow, 0,  lds_a[0][0], wave, lane);
  stage_khalf(B, bcol, 0,  lds_b[0][0], wave, lane);
  stage_khalf(A, brow, 32, lds_a[0][1], wave, lane);
  stage_khalf(B, bcol, 32, lds_b[0][1], wave, lane);

#define PHASE(KK)                                                               \
  {                                                                             \
    if (pf) { stage_khalf(A, brow, kn + (KK)*32, lds_a[n][KK], wave, lane);     \
              stage_khalf(B, bcol, kn + (KK)*32, lds_b[n][KK], wave, lane); }   \
    bf16x8 a0[4], a1[4], bv[4];                                                 \
    _Pragma("unroll")                                                           \
    for (int i = 0; i < 4; ++i)                                                 \
      a0[i] = *reinterpret_cast<const bf16x8*>(                                 \
          &lds_a[c][KK][wm*128 + i*16 + fr][rslot]);                            \
    _Pragma("unroll")                                                           \
    for (int i = 0; i < 4; ++i)                                                 \
      bv[i] = *reinterpret_cast<const bf16x8*>(                                 \
          &lds_b[c][KK][wn*64 + i*16 + fr][rslot]);                             \
    _Pragma("unroll")                                                           \
    for (int i = 0; i < 4; ++i)                                                 \
      a1[i] = *reinterpret_cast<const bf16x8*>(                                 \
          &lds_a[c][KK][wm*128 + 64 + i*16 + fr][rslot]);                       \
    asm volatile("s_waitcnt lgkmcnt(0)" ::: "memory");                          \
    __builtin_amdgcn_sched_barrier(0);                                          \
    __builtin_amdgcn_s_setprio(1);                                              \
    _Pragma("unroll")                                                           \
    for (int i = 0; i < 4; ++i) {                                               \
      _Pragma("unroll")                                                         \
      for (int j = 0; j < 4; ++j)                                               \
        acc[i][j] = __builtin_amdgcn_mfma_f32_16x16x32_bf16(                    \
            a0[i], bv[j], acc[i][j], 0, 0, 0);                                  \
    }                                                                           \
    _Pragma("unroll")                                                           \
    for (int i = 0; i < 4; ++i) {                                               \
      _Pragma("unroll")                                                         \
      for (int j = 0; j < 4; ++j)                                               \
        acc[4 + i][j] = __builtin_amdgcn_mfma_f32_16x16x32_bf16(                \
            a1[i], bv[j], acc[4 + i][j], 0, 0, 0);                              \
    }                                                                           \
    __builtin_amdgcn_s_setprio(0);                                              \
  }

  #pragma unroll 2
  for (int t = 0; t < DD / 64; ++t) {
    const int c = t & 1;
    const int n = c ^ 1;
    const int kn = (t + 1) * 64;
    const bool pf = (t < DD / 64 - 1);

    // ---- phase kk=0: guard A-k0,B-k0 of tile t (issued 2 phases ago) ----
    asm volatile("s_waitcnt vmcnt(4)" ::: "memory");
    __builtin_amdgcn_s_barrier();
    PHASE(0)

    // ---- phase kk=1: guard A-k1,B-k1 of tile t ----
    if (pf) { asm volatile("s_waitcnt vmcnt(4)" ::: "memory"); }
    else    { asm volatile("s_waitcnt vmcnt(0)" ::: "memory"); }
    __builtin_amdgcn_s_barrier();
    PHASE(1)
  }
#undef PHASE

  // ---- fused epilogue: v = exp(10*dot); row & col partial sums ----
  // C/D layout: col = fr, row = fq*4 + j (within each 16x16 fragment)
  float rowp[8][4];
  float colp[4];
  #pragma unroll
  for (int mi = 0; mi < 8; ++mi)
    #pragma unroll
    for (int j = 0; j < 4; ++j) rowp[mi][j] = 0.0f;
  #pragma unroll
  for (int ni = 0; ni < 4; ++ni) colp[ni] = 0.0f;

  #pragma unroll
  for (int mi = 0; mi < 8; ++mi) {
    #pragma unroll
    for (int ni = 0; ni < 4; ++ni) {
      #pragma unroll
      for (int j = 0; j < 4; ++j) {
        const float v = __expf(acc[mi][ni][j] * INV_T);
        rowp[mi][j] += v;
        colp[ni]    += v;
      }
    }
  }

  // row sums: reduce across 16 col-lanes, 1 atomic per row per wave
  #pragma unroll
  for (int mi = 0; mi < 8; ++mi) {
    #pragma unroll
    for (int j = 0; j < 4; ++j) {
      float r = rowp[mi][j];
      r += __shfl_xor(r, 1);
      r += __shfl_xor(r, 2);
      r += __shfl_xor(r, 4);
      r += __shfl_xor(r, 8);
      if (fr == 0) {
        atomicAdd(&row_sum[brow + wm * 128 + mi * 16 + fq * 4 + j], r);
      }
    }
  }
  // col sums: reduce across the 4 fq row-groups, 1 atomic per col per wave
  #pragma unroll
  for (int ni = 0; ni < 4; ++ni) {
    float cc = colp[ni];
    cc += __shfl_xor(cc, 16);
    cc += __shfl_xor(cc, 32);
    if (lane < 16) {
      atomicAdd(&col_sum[bcol + wn * 64 + ni * 16 + fr], cc);
    }
  }
}

// ---------- kernel 3: final scalar reduction (block 0 -> rows, block 1 -> cols) ----------
__global__ __launch_bounds__(1024) void fin_kernel(
    const float* __restrict__ row_sum, const float* __restrict__ col_sum,
    const float* __restrict__ log_diag, const float* __restrict__ exp_diag,
    float* __restrict__ out)
{
  const int tid  = threadIdx.x;
  const int lane = tid & 63;
  const int wave = tid >> 6;
  const float* sums = (blockIdx.x == 0) ? row_sum : col_sum;
  float a = 0.0f;
  #pragma unroll
  for (int kk = 0; kk < NN / 1024; ++kk) {
    const int i = tid + kk * 1024;
    a += logf(sums[i] - exp_diag[i]) - log_diag[i];
  }
  #pragma unroll
  for (int off = 1; off < 64; off <<= 1) a += __shfl_xor(a, off);
  __shared__ float r0[16];
  if (lane == 0) r0[wave] = a;
  __syncthreads();
  if (tid == 0) {
    float s = 0.0f;
    #pragma unroll
    for (int w = 0; w < 16; ++w) s += r0[w];
    out[blockIdx.x] = s;
  }
}

extern "C" void kernel_launch(void* const* d_in, const int* in_sizes, int n_in,
                              void* d_out, int out_size, void* d_ws, size_t ws_size,
                              hipStream_t stream) {
  const float* e1 = (const float*)d_in[0];
  const float* e2 = (const float*)d_in[1];
  float* out = (float*)d_out;

  char* ws = (char*)d_ws;
  unsigned short* e1n = (unsigned short*)ws;                            // 8 MB
  unsigned short* e2n = (unsigned short*)(ws + (size_t)NN * DD * 2);    // 8 MB
  float* log_diag = (float*)(ws + (size_t)NN * DD * 4);                 // 16 KB
  float* exp_diag = log_diag + NN;                                      // 16 KB
  float* row_sum  = exp_diag + NN;                                      // 16 KB
  float* col_sum  = row_sum + NN;                                       // 16 KB

  nrm_kernel<<<NN, 256, 0, stream>>>(e1, e2, e1n, e2n, log_diag, exp_diag,
                                     row_sum, col_sum);
  gemm_kernel<<<256, 512, 0, stream>>>(e1n, e2n, row_sum, col_sum);
  fin_kernel<<<2, 1024, 0, stream>>>(row_sum, col_sum, log_diag, exp_diag, out);
}